// Round 1
// baseline (206.518 us; speedup 1.0000x reference)
//
#include <hip/hip_runtime.h>
#include <hip/hip_bf16.h>

// ---- problem constants ----
constexpr int BATCH = 256;          // B
constexpr int MTOK  = 128;          // tokens per text
constexpr int DDIM  = 768;          // embedding dim
constexpr int NROWS = BATCH * MTOK; // 32768 rows of T (flattened)
constexpr int NV    = BATCH * DDIM;             // 196608 floats (v_final)
constexpr int NT    = NROWS * DDIM;             // 25165824 floats (T_fused)
constexpr int NV4   = NV / 4;                   // 49152
constexpr int TOT4  = (NV + NT) / 4;            // 6340608
constexpr float INV_TEMP = 1.0f / 0.07f;

typedef __bf16 bf16;
typedef __bf16 bf16x4 __attribute__((ext_vector_type(4)));
typedef __bf16 bf16x8 __attribute__((ext_vector_type(8)));
typedef float  f32x4  __attribute__((ext_vector_type(4)));

// ---- async global->LDS 16B copy (wave-uniform LDS base + lane*16) ----
typedef __attribute__((address_space(3))) char       lds_char;
typedef const __attribute__((address_space(1))) char g_char;

__device__ __forceinline__ void async16(const void* g, void* l) {
    __builtin_amdgcn_global_load_lds((g_char*)g, (lds_char*)l, 16, 0, 0);
}

// ============================================================
// Kernel 1: fp32 -> bf16 cast of v_final and T_fused (contiguous output)
// ============================================================
__global__ __launch_bounds__(256) void convert_kernel(
        const float4* __restrict__ v4,
        const float4* __restrict__ t4,
        bf16x4* __restrict__ out) {
    int i = blockIdx.x * 256 + threadIdx.x;
    if (i >= TOT4) return;
    float4 f = (i < NV4) ? v4[i] : t4[i - NV4];
    bf16x4 o;
    o.x = (bf16)f.x;
    o.y = (bf16)f.y;
    o.z = (bf16)f.z;
    o.w = (bf16)f.w;
    out[i] = o;
}

// ============================================================
// Kernel 2: C = A (256x768) * B^T (32768x768), fused max over m-blocks of 128
//   -> S[256][256] scaled by 1/TEMP.
// 128x128 block tile, BK=32, 4 waves each 64x64 via mfma_f32_16x16x32_bf16.
// ============================================================
__global__ __launch_bounds__(256) void gemm_max_kernel(
        const bf16* __restrict__ A,   // [256][768] row-major
        const bf16* __restrict__ Bm,  // [32768][768] row-major
        float* __restrict__ S) {      // [256][256]
    __shared__ char  ldsA[128 * 64];  // 128 rows x 32 bf16 (64 B/row)
    __shared__ char  ldsB[128 * 64];
    __shared__ float smax[128][2];

    const int jt   = blockIdx.x;   // 0..255  (one text j per block)
    const int it   = blockIdx.y;   // 0..1    (M tile)
    const int tid  = threadIdx.x;
    const int w    = tid >> 6;     // wave 0..3
    const int lane = tid & 63;
    const int wm   = w >> 1;       // wave row (0..1)
    const int wn   = w & 1;        // wave col (0..1)
    const int quad = lane >> 4;    // 0..3
    const int l15  = lane & 15;

    // staging: wave w covers tile rows [w*32, w*32+32) in two 16-row calls.
    const int srow   = w * 32 + (lane >> 2);     // row within tile (call 0)
    const int schunk = (lane & 3) * 8;           // bf16 element offset in BK
    const bf16* gA = A  + (size_t)(it * 128 + srow) * DDIM + schunk;
    const bf16* gB = Bm + ((size_t)jt * 128 + srow) * DDIM + schunk;
    char* lA = ldsA + (w * 32) * 64;             // + lane*16 implicit
    char* lB = ldsB + (w * 32) * 64;

    f32x4 acc[4][4] = {};

    for (int k0 = 0; k0 < DDIM; k0 += 32) {
        async16(gA + k0,            lA);
        async16(gA + 16 * DDIM + k0, lA + 16 * 64);
        async16(gB + k0,            lB);
        async16(gB + 16 * DDIM + k0, lB + 16 * 64);
        __syncthreads();   // drains vmcnt before barrier (m97 structure)

        bf16x8 af[4], bb[4];
#pragma unroll
        for (int t = 0; t < 4; ++t) {
            af[t] = *(const bf16x8*)(ldsA + (wm * 64 + t * 16 + l15) * 64 + quad * 16);
            bb[t] = *(const bf16x8*)(ldsB + (wn * 64 + t * 16 + l15) * 64 + quad * 16);
        }
#pragma unroll
        for (int tr = 0; tr < 4; ++tr)
#pragma unroll
            for (int tc = 0; tc < 4; ++tc)
                acc[tr][tc] = __builtin_amdgcn_mfma_f32_16x16x32_bf16(
                    af[tr], bb[tc], acc[tr][tc], 0, 0, 0);
        __syncthreads();
    }

    // epilogue: max over the 128 columns (= tokens m) of this block
    // C/D layout: col = lane&15, row = quad*4 + reg   [verified m89/m91]
#pragma unroll
    for (int tr = 0; tr < 4; ++tr) {
#pragma unroll
        for (int r = 0; r < 4; ++r) {
            float v = acc[tr][0][r];
            v = fmaxf(v, acc[tr][1][r]);
            v = fmaxf(v, acc[tr][2][r]);
            v = fmaxf(v, acc[tr][3][r]);
            v = fmaxf(v, __shfl_xor(v, 1, 64));
            v = fmaxf(v, __shfl_xor(v, 2, 64));
            v = fmaxf(v, __shfl_xor(v, 4, 64));
            v = fmaxf(v, __shfl_xor(v, 8, 64));
            if (l15 == 0) {
                int row = wm * 64 + tr * 16 + quad * 4 + r;
                smax[row][wn] = v;
            }
        }
    }
    __syncthreads();
    if (tid < 128) {
        float v = fmaxf(smax[tid][0], smax[tid][1]) * INV_TEMP;
        S[(size_t)(it * 128 + tid) * BATCH + jt] = v;
    }
}

// ============================================================
// Kernel 3: symmetric InfoNCE from S[256][256]
// loss = mean_i [ 0.5*(lse_row_i + lse_col_i) - S[i][i] ]
// ============================================================
__global__ __launch_bounds__(256) void ce_kernel(
        const float* __restrict__ S, float* __restrict__ out) {
    const int i = threadIdx.x;
    float mr = -3.4e38f, mc = -3.4e38f;
    for (int j = 0; j < BATCH; ++j) {
        mr = fmaxf(mr, S[i * BATCH + j]);
        mc = fmaxf(mc, S[j * BATCH + i]);
    }
    float sr = 0.f, sc = 0.f;
    for (int j = 0; j < BATCH; ++j) {
        sr += expf(S[i * BATCH + j] - mr);
        sc += expf(S[j * BATCH + i] - mc);
    }
    float term = 0.5f * ((mr + logf(sr)) + (mc + logf(sc))) - S[i * BATCH + i];

    // block-reduce sum
    for (int o = 32; o > 0; o >>= 1) term += __shfl_down(term, o, 64);
    __shared__ float partial[4];
    if ((i & 63) == 0) partial[i >> 6] = term;
    __syncthreads();
    if (i == 0) {
        float t = partial[0] + partial[1] + partial[2] + partial[3];
        out[0] = t / (float)BATCH;
    }
}

// ============================================================
extern "C" void kernel_launch(void* const* d_in, const int* in_sizes, int n_in,
                              void* d_out, int out_size, void* d_ws, size_t ws_size,
                              hipStream_t stream) {
    const float* v = (const float*)d_in[0];   // [256][768] fp32
    const float* T = (const float*)d_in[1];   // [256][128][768] fp32

    // workspace layout: [ Ab bf16 NV | Tb bf16 NT | S f32 256*256 ]
    bf16* Ab = (bf16*)d_ws;
    bf16* Tb = Ab + NV;
    float* S = (float*)((char*)d_ws + (size_t)(NV + NT) * sizeof(bf16));

    convert_kernel<<<(TOT4 + 255) / 256, 256, 0, stream>>>(
        (const float4*)v, (const float4*)T, (bf16x4*)Ab);

    gemm_max_kernel<<<dim3(256, 2), 256, 0, stream>>>(Ab, Tb, S);

    ce_kernel<<<1, 256, 0, stream>>>(S, (float*)d_out);
}

// Round 2
// 204.655 us; speedup vs baseline: 1.0091x; 1.0091x over previous
//
#include <hip/hip_runtime.h>
#include <hip/hip_bf16.h>

// ---- problem constants ----
constexpr int BATCH = 256;          // B
constexpr int MTOK  = 128;          // tokens per text
constexpr int DDIM  = 768;          // embedding dim
constexpr int NROWS = BATCH * MTOK; // 32768 rows of T (flattened)
constexpr int NV    = BATCH * DDIM;             // 196608 floats (v_final)
constexpr int NT    = NROWS * DDIM;             // 25165824 floats (T_fused)
constexpr int NV4   = NV / 4;                   // 49152
constexpr int TOT4  = (NV + NT) / 4;            // 6340608
constexpr float INV_TEMP = 1.0f / 0.07f;

typedef __bf16 bf16;
typedef __bf16 bf16x4 __attribute__((ext_vector_type(4)));
typedef __bf16 bf16x8 __attribute__((ext_vector_type(8)));
typedef float  f32x4  __attribute__((ext_vector_type(4)));

// ---- async global->LDS 16B copy (wave-uniform LDS base + lane*16) ----
typedef __attribute__((address_space(3))) char       lds_char;
typedef const __attribute__((address_space(1))) char g_char;

__device__ __forceinline__ void async16(const void* g, void* l) {
    __builtin_amdgcn_global_load_lds((g_char*)g, (lds_char*)l, 16, 0, 0);
}

// ============================================================
// Kernel 1: fp32 -> bf16 cast of v_final and T_fused (contiguous output)
// ============================================================
__global__ __launch_bounds__(256) void convert_kernel(
        const float4* __restrict__ v4,
        const float4* __restrict__ t4,
        bf16x4* __restrict__ out) {
    int i = blockIdx.x * 256 + threadIdx.x;
    if (i >= TOT4) return;
    float4 f = (i < NV4) ? v4[i] : t4[i - NV4];
    bf16x4 o;
    o.x = (bf16)f.x;
    o.y = (bf16)f.y;
    o.z = (bf16)f.z;
    o.w = (bf16)f.w;
    out[i] = o;
}

// ============================================================
// Kernel 2: C = A (256x768) * B^T (32768x768), fused max over m-blocks of 128
//   -> S[256][256] and ST=S^T, both scaled by 1/TEMP.
// 128x128 block tile, BK=64, 4 waves each 64x64 via mfma_f32_16x16x32_bf16.
// ============================================================
__global__ __launch_bounds__(256) void gemm_max_kernel(
        const bf16* __restrict__ A,   // [256][768] row-major
        const bf16* __restrict__ Bm,  // [32768][768] row-major
        float* __restrict__ S,        // [256][256]  S[i][j]
        float* __restrict__ ST) {     // [256][256]  ST[j][i] = S[i][j]
    __shared__ char  ldsA[128 * 128];  // 128 rows x 64 bf16 (128 B/row)
    __shared__ char  ldsB[128 * 128];
    __shared__ float smax[128][2];

    const int jt   = blockIdx.x;   // 0..255  (one text j per block)
    const int it   = blockIdx.y;   // 0..1    (M tile)
    const int tid  = threadIdx.x;
    const int w    = tid >> 6;     // wave 0..3
    const int lane = tid & 63;
    const int wm   = w >> 1;       // wave row (0..1)
    const int wn   = w & 1;        // wave col (0..1)
    const int quad = lane >> 4;    // 0..3
    const int l15  = lane & 15;

    // staging: wave w covers tile rows [w*32, w*32+32), 8 rows per call,
    // lane l -> row (l>>3), 16B chunk (l&7) of the 128 B row slab.
    const int srow   = w * 32 + (lane >> 3);
    const int schunk = (lane & 7) * 8;           // bf16 element offset in BK=64
    const bf16* gA = A  + (size_t)(it * 128 + srow) * DDIM + schunk;
    const bf16* gB = Bm + ((size_t)jt * 128 + srow) * DDIM + schunk;
    char* lA = ldsA + (w * 32) * 128;            // + lane*16 implicit
    char* lB = ldsB + (w * 32) * 128;

    f32x4 acc[4][4] = {};

    for (int k0 = 0; k0 < DDIM; k0 += 64) {
#pragma unroll
        for (int q = 0; q < 4; ++q) {
            async16(gA + (size_t)q * 8 * DDIM + k0, lA + q * 1024);
            async16(gB + (size_t)q * 8 * DDIM + k0, lB + q * 1024);
        }
        __syncthreads();   // drains vmcnt before barrier (m97 structure)

        bf16x8 af[2][4], bb[2][4];
#pragma unroll
        for (int h = 0; h < 2; ++h)
#pragma unroll
            for (int t = 0; t < 4; ++t) {
                af[h][t] = *(const bf16x8*)(ldsA + (wm * 64 + t * 16 + l15) * 128 + h * 64 + quad * 16);
                bb[h][t] = *(const bf16x8*)(ldsB + (wn * 64 + t * 16 + l15) * 128 + h * 64 + quad * 16);
            }
#pragma unroll
        for (int h = 0; h < 2; ++h)
#pragma unroll
            for (int tr = 0; tr < 4; ++tr)
#pragma unroll
                for (int tc = 0; tc < 4; ++tc)
                    acc[tr][tc] = __builtin_amdgcn_mfma_f32_16x16x32_bf16(
                        af[h][tr], bb[h][tc], acc[tr][tc], 0, 0, 0);
        __syncthreads();
    }

    // epilogue: max over the 128 columns (= tokens m) of this block
    // C/D layout: col = lane&15, row = quad*4 + reg   [verified m89/m91]
#pragma unroll
    for (int tr = 0; tr < 4; ++tr) {
#pragma unroll
        for (int r = 0; r < 4; ++r) {
            float v = acc[tr][0][r];
            v = fmaxf(v, acc[tr][1][r]);
            v = fmaxf(v, acc[tr][2][r]);
            v = fmaxf(v, acc[tr][3][r]);
            v = fmaxf(v, __shfl_xor(v, 1, 64));
            v = fmaxf(v, __shfl_xor(v, 2, 64));
            v = fmaxf(v, __shfl_xor(v, 4, 64));
            v = fmaxf(v, __shfl_xor(v, 8, 64));
            if (l15 == 0) {
                int row = wm * 64 + tr * 16 + quad * 4 + r;
                smax[row][wn] = v;
            }
        }
    }
    __syncthreads();
    if (tid < 128) {
        float v = fmaxf(smax[tid][0], smax[tid][1]) * INV_TEMP;
        int row = it * 128 + tid;                  // i index
        S [(size_t)row * BATCH + jt] = v;          // row-major (stride-256 store, tiny)
        ST[(size_t)jt  * BATCH + row] = v;         // coalesced across tid
    }
}

// ============================================================
// Kernel 3: symmetric InfoNCE from S[256][256] (+ transpose copy ST)
// loss = mean_i [ 0.5*(lse_row_i + lse_col_i) - S[i][i] ]
// All global reads coalesced: thread i always reads column i of a
// row-major matrix (lane-contiguous addresses).
// ============================================================
__global__ __launch_bounds__(256) void ce_kernel(
        const float* __restrict__ S,   // col-lse source: S[j*256+i]
        const float* __restrict__ ST,  // row-lse source: ST[j*256+i] = S[i][j]
        float* __restrict__ out) {
    const int i = threadIdx.x;
    float mr = -3.4e38f, mc = -3.4e38f;
    for (int j = 0; j < BATCH; ++j) {
        mr = fmaxf(mr, ST[j * BATCH + i]);   // max over row i of S
        mc = fmaxf(mc, S [j * BATCH + i]);   // max over col i of S
    }
    float sr = 0.f, sc = 0.f;
    for (int j = 0; j < BATCH; ++j) {
        sr += expf(ST[j * BATCH + i] - mr);
        sc += expf(S [j * BATCH + i] - mc);
    }
    float term = 0.5f * ((mr + logf(sr)) + (mc + logf(sc))) - S[(size_t)i * BATCH + i];

    // block-reduce sum
    for (int o = 32; o > 0; o >>= 1) term += __shfl_down(term, o, 64);
    __shared__ float partial[4];
    if ((i & 63) == 0) partial[i >> 6] = term;
    __syncthreads();
    if (i == 0) {
        float t = partial[0] + partial[1] + partial[2] + partial[3];
        out[0] = t / (float)BATCH;
    }
}

// ============================================================
extern "C" void kernel_launch(void* const* d_in, const int* in_sizes, int n_in,
                              void* d_out, int out_size, void* d_ws, size_t ws_size,
                              hipStream_t stream) {
    const float* v = (const float*)d_in[0];   // [256][768] fp32
    const float* T = (const float*)d_in[1];   // [256][128][768] fp32

    // workspace layout: [ Ab bf16 NV | Tb bf16 NT | S f32 256*256 | ST f32 256*256 ]
    bf16* Ab = (bf16*)d_ws;
    bf16* Tb = Ab + NV;
    float* S  = (float*)((char*)d_ws + (size_t)(NV + NT) * sizeof(bf16));
    float* ST = S + BATCH * BATCH;

    convert_kernel<<<(TOT4 + 255) / 256, 256, 0, stream>>>(
        (const float4*)v, (const float4*)T, (bf16x4*)Ab);

    gemm_max_kernel<<<dim3(256, 2), 256, 0, stream>>>(Ab, Tb, S, ST);

    ce_kernel<<<1, 256, 0, stream>>>(S, ST, (float*)d_out);
}

// Round 3
// 197.263 us; speedup vs baseline: 1.0469x; 1.0375x over previous
//
#include <hip/hip_runtime.h>
#include <hip/hip_bf16.h>

// ---- problem constants ----
constexpr int BATCH = 256;          // B
constexpr int MTOK  = 128;          // tokens per text
constexpr int DDIM  = 768;          // embedding dim
constexpr float INV_TEMP = 1.0f / 0.07f;

typedef __bf16 bf16;
typedef __bf16 bf16x8 __attribute__((ext_vector_type(8)));
typedef float  f32x4  __attribute__((ext_vector_type(4)));

// ============================================================
// Fused kernel: for one text j (blockIdx.x):
//   sim[i, m] = <v[i,:], T[j,m,:]>  for all i in 0..255, m in 0..127
//   S[i][j] = max_m sim * (1/TEMP),  ST[j][i] = same.
// fp32 inputs read directly from HBM (T read EXACTLY ONCE total),
// converted to bf16 in registers, staged to LDS with XOR-16B swizzle.
// Tile: M=256 x N=128, BK=64; 8 waves each compute 64x64 via
// mfma_f32_16x16x32_bf16. Register prefetch of next K-slab overlaps MFMA.
// ============================================================
__global__ __launch_bounds__(512, 2) void fused_gemm_max_kernel(
        const float* __restrict__ V,   // [256][768]  v_final
        const float* __restrict__ T,   // [32768][768] T_fused flattened
        float* __restrict__ S,         // [256][256]  S[i][j]
        float* __restrict__ ST) {      // [256][256]  ST[j][i]
    __shared__ char  lds[49152];       // A: 256 rows x 128 B @0 ; B: 128 rows x 128 B @32768
    __shared__ float smax[256][2];

    const int jt   = blockIdx.x;       // text index j
    const int tid  = threadIdx.x;
    const int w    = tid >> 6;         // wave 0..7
    const int lane = tid & 63;
    const int wr   = w >> 1;           // wave M-stripe 0..3
    const int wn   = w & 1;            // wave N-stripe 0..1
    const int quad = lane >> 4;
    const int l15  = lane & 15;

    // --- staging slots: 6 x (16B-bf16 chunk = 8 K-elems) per thread per iter.
    // chunk c = s*512 + tid; c<2048 -> A (V row c>>3), else B (T row (c-2048)>>3).
    const float* gsrc[6];
    int loff[6];
#pragma unroll
    for (int s = 0; s < 6; ++s) {
        int c   = s * 512 + tid;
        int isB = (c >= 2048);
        int cc  = isB ? (c - 2048) : c;
        int row = cc >> 3, kp = cc & 7;
        const float* base = isB ? (T + ((size_t)(jt * MTOK + row)) * DDIM)
                                : (V + (size_t)row * DDIM);
        gsrc[s] = base + kp * 8;
        loff[s] = (isB ? 32768 : 0) + row * 128 + ((kp ^ (row & 7)) << 4);
    }

    // --- frag ds_read offsets (K-invariant; swizzle matches staging) ---
    int aoff[2][4], boff[2][4];
#pragma unroll
    for (int h = 0; h < 2; ++h)
#pragma unroll
        for (int t = 0; t < 4; ++t) {
            int kp = h * 4 + quad;
            int ar = wr * 64 + t * 16 + l15;
            aoff[h][t] = ar * 128 + ((kp ^ (ar & 7)) << 4);
            int br = wn * 64 + t * 16 + l15;
            boff[h][t] = 32768 + br * 128 + ((kp ^ (br & 7)) << 4);
        }

    f32x4 acc[4][4] = {};

    // preload K-slab 0
    float4 pre[6][2];
#pragma unroll
    for (int s = 0; s < 6; ++s) {
        pre[s][0] = *(const float4*)(gsrc[s]);
        pre[s][1] = *(const float4*)(gsrc[s] + 4);
    }

    for (int kk = 0; kk < 12; ++kk) {
        // convert staged fp32 -> bf16, write to LDS (b128, swizzled, conflict-free)
#pragma unroll
        for (int s = 0; s < 6; ++s) {
            bf16x8 o;
            o[0] = (bf16)pre[s][0].x; o[1] = (bf16)pre[s][0].y;
            o[2] = (bf16)pre[s][0].z; o[3] = (bf16)pre[s][0].w;
            o[4] = (bf16)pre[s][1].x; o[5] = (bf16)pre[s][1].y;
            o[6] = (bf16)pre[s][1].z; o[7] = (bf16)pre[s][1].w;
            *(bf16x8*)(lds + loff[s]) = o;
        }
        __syncthreads();

        // issue next slab's global loads; consumed at next iter's ds_write
        if (kk < 11) {
#pragma unroll
            for (int s = 0; s < 6; ++s) {
                const float* p = gsrc[s] + (kk + 1) * 64;
                pre[s][0] = *(const float4*)(p);
                pre[s][1] = *(const float4*)(p + 4);
            }
        }

#pragma unroll
        for (int h = 0; h < 2; ++h) {
            bf16x8 af[4], bb[4];
#pragma unroll
            for (int t = 0; t < 4; ++t) {
                af[t] = *(const bf16x8*)(lds + aoff[h][t]);
                bb[t] = *(const bf16x8*)(lds + boff[h][t]);
            }
#pragma unroll
            for (int tr = 0; tr < 4; ++tr)
#pragma unroll
                for (int tc = 0; tc < 4; ++tc)
                    acc[tr][tc] = __builtin_amdgcn_mfma_f32_16x16x32_bf16(
                        af[tr], bb[tc], acc[tr][tc], 0, 0, 0);
        }
        __syncthreads();
    }

    // epilogue: max over this j's 128 tokens (cols = wn*64 + tc*16 + l15)
    // C/D layout: col = lane&15, row = quad*4 + reg   [verified m89/m91]
#pragma unroll
    for (int tr = 0; tr < 4; ++tr) {
#pragma unroll
        for (int r = 0; r < 4; ++r) {
            float v = acc[tr][0][r];
            v = fmaxf(v, acc[tr][1][r]);
            v = fmaxf(v, acc[tr][2][r]);
            v = fmaxf(v, acc[tr][3][r]);
            v = fmaxf(v, __shfl_xor(v, 1, 64));
            v = fmaxf(v, __shfl_xor(v, 2, 64));
            v = fmaxf(v, __shfl_xor(v, 4, 64));
            v = fmaxf(v, __shfl_xor(v, 8, 64));
            if (l15 == 0) {
                int row = wr * 64 + tr * 16 + quad * 4 + r;
                smax[row][wn] = v;
            }
        }
    }
    __syncthreads();
    if (tid < BATCH) {
        float v = fmaxf(smax[tid][0], smax[tid][1]) * INV_TEMP;
        S [(size_t)tid * BATCH + jt] = v;   // column write (tiny)
        ST[(size_t)jt  * BATCH + tid] = v;  // coalesced
    }
}

// ============================================================
// CE kernel: loss = mean_i [ 0.5*(lse_row_i + lse_col_i) - S[i][i] ]
// thread i reads column i of row-major S and ST -> fully coalesced.
// ============================================================
__global__ __launch_bounds__(256) void ce_kernel(
        const float* __restrict__ S,   // col-lse source
        const float* __restrict__ ST,  // row-lse source (ST[j][i] = S[i][j])
        float* __restrict__ out) {
    const int i = threadIdx.x;
    float mr = -3.4e38f, mc = -3.4e38f;
    for (int j = 0; j < BATCH; ++j) {
        mr = fmaxf(mr, ST[j * BATCH + i]);
        mc = fmaxf(mc, S [j * BATCH + i]);
    }
    float sr = 0.f, sc = 0.f;
    for (int j = 0; j < BATCH; ++j) {
        sr += expf(ST[j * BATCH + i] - mr);
        sc += expf(S [j * BATCH + i] - mc);
    }
    float term = 0.5f * ((mr + logf(sr)) + (mc + logf(sc))) - S[(size_t)i * BATCH + i];

    for (int o = 32; o > 0; o >>= 1) term += __shfl_down(term, o, 64);
    __shared__ float partial[4];
    if ((i & 63) == 0) partial[i >> 6] = term;
    __syncthreads();
    if (i == 0) {
        float t = partial[0] + partial[1] + partial[2] + partial[3];
        out[0] = t / (float)BATCH;
    }
}

// ============================================================
extern "C" void kernel_launch(void* const* d_in, const int* in_sizes, int n_in,
                              void* d_out, int out_size, void* d_ws, size_t ws_size,
                              hipStream_t stream) {
    const float* v = (const float*)d_in[0];   // [256][768] fp32
    const float* T = (const float*)d_in[1];   // [256][128][768] fp32

    // workspace: [ S f32 256*256 | ST f32 256*256 ]
    float* S  = (float*)d_ws;
    float* ST = S + BATCH * BATCH;

    fused_gemm_max_kernel<<<256, 512, 0, stream>>>(v, T, S, ST);
    ce_kernel<<<1, 256, 0, stream>>>(S, ST, (float*)d_out);
}

// Round 4
// 168.864 us; speedup vs baseline: 1.2230x; 1.1682x over previous
//
#include <hip/hip_runtime.h>
#include <hip/hip_bf16.h>

// ---- problem constants ----
constexpr int BATCH = 256;          // B
constexpr int MTOK  = 128;          // tokens per text
constexpr int DDIM  = 768;          // embedding dim
constexpr int NV    = BATCH * DDIM; // v_final elems
constexpr float INV_TEMP = 1.0f / 0.07f;

typedef __bf16 bf16;
typedef __bf16 bf16x4 __attribute__((ext_vector_type(4)));
typedef __bf16 bf16x8 __attribute__((ext_vector_type(8)));
typedef float  f32x4  __attribute__((ext_vector_type(4)));

typedef __attribute__((address_space(3))) char       lds_char;
typedef const __attribute__((address_space(1))) char g_char;

__device__ __forceinline__ void async16(const void* g, void* l) {
    __builtin_amdgcn_global_load_lds((g_char*)g, (lds_char*)l, 16, 0, 0);
}

// ============================================================
// Kernel 0: V fp32 -> bf16 (768 KB -> 384 KB, L2-resident afterwards)
// ============================================================
__global__ __launch_bounds__(256) void convert_v_kernel(
        const float4* __restrict__ v4, bf16x4* __restrict__ out) {
    int i = blockIdx.x * 256 + threadIdx.x;
    if (i >= NV / 4) return;
    float4 f = v4[i];
    bf16x4 o;
    o.x = (bf16)f.x; o.y = (bf16)f.y; o.z = (bf16)f.z; o.w = (bf16)f.w;
    out[i] = o;
}

// ============================================================
// Kernel 1: block (j, mh) computes sim[i, m] for all i, m in 64-token half mh;
//   Sp[mh][j][i] = max_m sim * (1/TEMP).
// M=256 x N=64, BK=64, 12 iters. 4 waves, each 64x64 (acc 4x4).
// A (V bf16): global_load_lds, DOUBLE-BUFFERED (drain off critical path).
// B (T fp32): register prefetch -> convert -> ds_write, single-buffered.
// LDS rows 64 B (2 K-half slabs) -> 2-way bank aliasing = free (m136/m97).
// ============================================================
__global__ __launch_bounds__(256, 2) void gemm_max_kernel(
        const bf16*  __restrict__ Vb,  // [256][768] bf16
        const float* __restrict__ T,   // [32768][768] fp32
        float* __restrict__ Sp) {      // [2][256][256]  Sp[mh][j][i]
    // A: 2 bufs x (2 khalf x 256 rows x 64 B) = 2 x 32768
    // B:           2 khalf x  64 rows x 64 B  = 8192   @ 65536
    __shared__ char  lds[65536 + 8192];
    __shared__ float smax[256];

    const int jt   = blockIdx.x >> 1;   // text j
    const int mh   = blockIdx.x & 1;    // token half
    const int tid  = threadIdx.x;
    const int w    = tid >> 6;          // wave 0..3 -> M stripe
    const int lane = tid & 63;
    const int quad = lane >> 4;
    const int l15  = lane & 15;

    // --- A staging: 8 async16 calls/thread/iter; chunk c = q*256+tid ---
    // LDS offset inside buf = c*16 (== khalf*16384 + row*64 + sub*16)
    const bf16* gA[8];
#pragma unroll
    for (int q = 0; q < 8; ++q) {
        int c = q * 256 + tid;
        int row = (c >> 2) & 255, sub = c & 3, kh = c >> 10;
        gA[q] = Vb + (size_t)row * DDIM + kh * 32 + sub * 8;
    }
    const int ldsAbase = (tid >> 6) * 1024;  // + q*4096, wave-uniform

    // --- B staging: 2 chunks/thread/iter ---
    const float* gB[2];
    int boffw[2];
#pragma unroll
    for (int q = 0; q < 2; ++q) {
        int c = q * 256 + tid;
        int row = c >> 3, kp = c & 7;
        gB[q] = T + (size_t)(jt * MTOK + mh * 64 + row) * DDIM + kp * 8;
        boffw[q] = 65536 + (kp >> 2) * 4096 + row * 64 + (kp & 3) * 16;
    }

    // --- frag read offsets (buf term added in loop) ---
    int aoff[2][4], boff[2][4];
#pragma unroll
    for (int h = 0; h < 2; ++h)
#pragma unroll
        for (int t = 0; t < 4; ++t) {
            int ar = w * 64 + t * 16 + l15;
            aoff[h][t] = h * 16384 + ar * 64 + quad * 16;
            int br = t * 16 + l15;
            boff[h][t] = 65536 + h * 4096 + br * 64 + quad * 16;
        }

    f32x4 acc[4][4] = {};
    float4 pre[2][2];

    // prologue: A slab 0 -> buf 0; B slab 0 -> regs
#pragma unroll
    for (int q = 0; q < 8; ++q)
        async16(gA[q], lds + q * 4096 + ldsAbase);
#pragma unroll
    for (int q = 0; q < 2; ++q) {
        pre[q][0] = *(const float4*)(gB[q]);
        pre[q][1] = *(const float4*)(gB[q] + 4);
    }

    for (int kk = 0; kk < 12; ++kk) {
        const int buf = (kk & 1) * 32768;
        // convert B regs -> LDS
#pragma unroll
        for (int q = 0; q < 2; ++q) {
            bf16x8 o;
            o[0] = (bf16)pre[q][0].x; o[1] = (bf16)pre[q][0].y;
            o[2] = (bf16)pre[q][0].z; o[3] = (bf16)pre[q][0].w;
            o[4] = (bf16)pre[q][1].x; o[5] = (bf16)pre[q][1].y;
            o[6] = (bf16)pre[q][1].z; o[7] = (bf16)pre[q][1].w;
            *(bf16x8*)(lds + boffw[q]) = o;
        }
        __syncthreads();   // A asyncs (issued last iter) + B writes visible

        if (kk < 11) {
            const int nbuf = ((kk + 1) & 1) * 32768;
            // A slab kk+1 -> other buf (drained at NEXT sync -> latency hidden)
#pragma unroll
            for (int q = 0; q < 8; ++q)
                async16(gA[q] + (kk + 1) * 64, lds + nbuf + q * 4096 + ldsAbase);
            // B slab kk+1 -> regs (consumed after next sync2)
#pragma unroll
            for (int q = 0; q < 2; ++q) {
                const float* p = gB[q] + (kk + 1) * 64;
                pre[q][0] = *(const float4*)(p);
                pre[q][1] = *(const float4*)(p + 4);
            }
        }

#pragma unroll
        for (int h = 0; h < 2; ++h) {
            bf16x8 af[4], bb[4];
#pragma unroll
            for (int t = 0; t < 4; ++t) {
                af[t] = *(const bf16x8*)(lds + buf + aoff[h][t]);
                bb[t] = *(const bf16x8*)(lds + boff[h][t]);
            }
#pragma unroll
            for (int tr = 0; tr < 4; ++tr)
#pragma unroll
                for (int tc = 0; tc < 4; ++tc)
                    acc[tr][tc] = __builtin_amdgcn_mfma_f32_16x16x32_bf16(
                        af[tr], bb[tc], acc[tr][tc], 0, 0, 0);
        }
        __syncthreads();   // B region reuse + A cross-buf safety
    }

    // epilogue: max over this half's 64 tokens (cols = tc*16 + l15)
    // C/D layout: col = lane&15, row = quad*4 + reg   [m89/m91]
#pragma unroll
    for (int tr = 0; tr < 4; ++tr) {
#pragma unroll
        for (int r = 0; r < 4; ++r) {
            float v = acc[tr][0][r];
            v = fmaxf(v, acc[tr][1][r]);
            v = fmaxf(v, acc[tr][2][r]);
            v = fmaxf(v, acc[tr][3][r]);
            v = fmaxf(v, __shfl_xor(v, 1, 64));
            v = fmaxf(v, __shfl_xor(v, 2, 64));
            v = fmaxf(v, __shfl_xor(v, 4, 64));
            v = fmaxf(v, __shfl_xor(v, 8, 64));
            if (l15 == 0)
                smax[w * 64 + tr * 16 + quad * 4 + r] = v;
        }
    }
    __syncthreads();
    Sp[(size_t)mh * BATCH * BATCH + (size_t)jt * BATCH + tid] = smax[tid] * INV_TEMP;
}

// ============================================================
// CE stage 1: block t (256 blocks x 1 wave) computes
//   partial[t] = 0.5*(lse_j S[t][j] + lse_i S[i][t]) - S[t][t]
// where S[i][j] = max(Sp[0][j][i], Sp[1][j][i]).
// ============================================================
__global__ __launch_bounds__(64) void ce1_kernel(
        const float* __restrict__ Sp, float* __restrict__ partial) {
    const int t = blockIdx.x;
    const int l = threadIdx.x;
    const float* Sp0 = Sp;
    const float* Sp1 = Sp + BATCH * BATCH;

    float vr[4], vc[4];
#pragma unroll
    for (int p = 0; p < 4; ++p) {
        int j = p * 64 + l;
        vr[p] = fmaxf(Sp0[j * BATCH + t], Sp1[j * BATCH + t]);  // S[t][j]
        int i = p * 64 + l;
        vc[p] = fmaxf(Sp0[t * BATCH + i], Sp1[t * BATCH + i]);  // S[i][t]
    }
    float mr = fmaxf(fmaxf(vr[0], vr[1]), fmaxf(vr[2], vr[3]));
    float mc = fmaxf(fmaxf(vc[0], vc[1]), fmaxf(vc[2], vc[3]));
    for (int o = 32; o > 0; o >>= 1) {
        mr = fmaxf(mr, __shfl_xor(mr, o, 64));
        mc = fmaxf(mc, __shfl_xor(mc, o, 64));
    }
    float sr = 0.f, sc = 0.f;
#pragma unroll
    for (int p = 0; p < 4; ++p) {
        sr += expf(vr[p] - mr);
        sc += expf(vc[p] - mc);
    }
    for (int o = 32; o > 0; o >>= 1) {
        sr += __shfl_xor(sr, o, 64);
        sc += __shfl_xor(sc, o, 64);
    }
    if (l == 0) {
        float diag = fmaxf(Sp0[t * BATCH + t], Sp1[t * BATCH + t]);
        partial[t] = 0.5f * ((mr + logf(sr)) + (mc + logf(sc))) - diag;
    }
}

// ============================================================
// CE stage 2: mean of 256 partials
// ============================================================
__global__ __launch_bounds__(256) void ce2_kernel(
        const float* __restrict__ partial, float* __restrict__ out) {
    const int i = threadIdx.x;
    float term = partial[i];
    for (int o = 32; o > 0; o >>= 1) term += __shfl_down(term, o, 64);
    __shared__ float ps[4];
    if ((i & 63) == 0) ps[i >> 6] = term;
    __syncthreads();
    if (i == 0) out[0] = (ps[0] + ps[1] + ps[2] + ps[3]) / (float)BATCH;
}

// ============================================================
extern "C" void kernel_launch(void* const* d_in, const int* in_sizes, int n_in,
                              void* d_out, int out_size, void* d_ws, size_t ws_size,
                              hipStream_t stream) {
    const float* v = (const float*)d_in[0];   // [256][768] fp32
    const float* T = (const float*)d_in[1];   // [256][128][768] fp32

    // ws: [ Vb bf16 NV | Sp f32 2*256*256 | partial f32 256 ]
    bf16*  Vb = (bf16*)d_ws;
    float* Sp = (float*)((char*)d_ws + (size_t)NV * sizeof(bf16));
    float* partial = Sp + 2 * BATCH * BATCH;

    convert_v_kernel<<<(NV / 4 + 255) / 256, 256, 0, stream>>>(
        (const float4*)v, (bf16x4*)Vb);
    gemm_max_kernel<<<512, 256, 0, stream>>>(Vb, T, Sp);
    ce1_kernel<<<256, 64, 0, stream>>>(Sp, partial);
    ce2_kernel<<<1, 256, 0, stream>>>(partial, (float*)d_out);
}